// Round 1
// baseline (218.151 us; speedup 1.0000x reference)
//
#include <hip/hip_runtime.h>
#include <math.h>

#define NB 256
#define NIMG 1561
#define RIRLEN 8000
#define FLEN 81
#define PADI 40
#define NTHREADS 1024

// ---------------------------------------------------------------------------
// Compile-time image-lattice table: all g in [-10,10]^3 with |g|_1 <= 10,
// lexicographic (x,y,z) order like np.meshgrid(ij).  Packed:
//   bits 0-4: x+10, 5-9: y+10, 10-14: z+10, 15-19: |g|_1
// ---------------------------------------------------------------------------
struct ImgTab { unsigned int v[NIMG]; };

constexpr ImgTab build_tab() {
    ImgTab t{};
    int n = 0;
    for (int x = -10; x <= 10; ++x)
        for (int y = -10; y <= 10; ++y)
            for (int z = -10; z <= 10; ++z) {
                int ax = x < 0 ? -x : x;
                int ay = y < 0 ? -y : y;
                int az = z < 0 ? -z : z;
                int l1 = ax + ay + az;
                if (l1 <= 10) {
                    t.v[n++] = (unsigned)(x + 10) | ((unsigned)(y + 10) << 5) |
                               ((unsigned)(z + 10) << 10) | ((unsigned)l1 << 15);
                }
            }
    return t;
}

constexpr int tab_count() {
    int n = 0;
    for (int x = -10; x <= 10; ++x)
        for (int y = -10; y <= 10; ++y)
            for (int z = -10; z <= 10; ++z) {
                int ax = x < 0 ? -x : x;
                int ay = y < 0 ? -y : y;
                int az = z < 0 ? -z : z;
                if (ax + ay + az <= 10) ++n;
            }
    return n;
}
static_assert(tab_count() == NIMG, "image count mismatch");

__constant__ ImgTab c_tab = build_tab();

__global__ __launch_bounds__(NTHREADS) void
rir_kernel(const float* __restrict__ in, float* __restrict__ out) {
    __shared__ float s_rir[RIRLEN];
    __shared__ float s_cj[FLEN];   // cos(pi*(j-40)/40)
    __shared__ float s_sj[FLEN];   // sin(pi*(j-40)/40)
    __shared__ float s_trpow[11];  // tr^k

    const int b   = blockIdx.x;
    const int tid = threadIdx.x;
    const float* p = in + b * 10;

    // zero the LDS accumulator
    for (int i = tid; i < RIRLEN; i += NTHREADS) s_rir[i] = 0.0f;

    // per-tap hann angle table
    if (tid < FLEN) {
        float a = (float)(tid - PADI) * (1.0f / 40.0f);
        s_cj[tid] = cospif(a);
        s_sj[tid] = sinpif(a);
    }
    // transmission powers tr^0..tr^10
    if (tid == 0) {
        float tr = sqrtf(1.0f - p[9]);
        float pw = 1.0f;
        for (int k = 0; k <= 10; ++k) { s_trpow[k] = pw; pw *= tr; }
    }
    __syncthreads();

    const float rx = p[0], ry = p[1], rz = p[2];
    const float mx = p[3] * rx, my = p[4] * ry, mz = p[5] * rz;
    const float sx = p[6] * rx, sy = p[7] * ry, sz = p[8] * rz;

    const float FS = 16000.0f;
    const float C  = 343.0f;
    const float INV_PI = 0.31830988618379067154f;

    for (int i = tid; i < NIMG; i += NTHREADS) {
        unsigned v = c_tab.v[i];
        int gx = (int)(v & 31u) - 10;
        int gy = (int)((v >> 5) & 31u) - 10;
        int gz = (int)((v >> 10) & 31u) - 10;
        int l1 = (int)(v >> 15);

        float ix = (gx & 1) ? rx * (float)(gx + 1) - sx : rx * (float)gx + sx;
        float iy = (gy & 1) ? ry * (float)(gy + 1) - sy : ry * (float)gy + sy;
        float iz = (gz & 1) ? rz * (float)(gz + 1) - sz : rz * (float)gz + sz;

        float dx = ix - mx, dy = iy - my, dz = iz - mz;
        float dist = sqrtf(dx * dx + dy * dy + dz * dz);

        float amp   = s_trpow[l1] / dist;
        float delay = dist * FS / C;
        float dlc   = ceilf(delay);
        float frac  = dlc - delay;            // in [0,1), exact (Sterbenz)
        int   base  = (int)dlc - PADI;
        if (base >= RIRLEN) continue;         // window entirely past the RIR

        if (frac == 0.0f) {
            // sinc hits exactly the integer grid: single spike of `amp`
            int idx = base + PADI;
            if (idx >= 0 && idx < RIRLEN) atomicAdd(&s_rir[idx], amp);
            continue;
        }

        // amp * sin(pi*frac)/pi ; per-tap sinc = this * (-1)^j / x
        float asp = amp * sinpif(frac) * INV_PI;
        float ch  = cospif(frac * 0.025f);    // cos(pi*frac/40)
        float sh  = sinpif(frac * 0.025f);

        // j = 80 has x = 40+frac > 40 -> hann window = 0; loop 80 taps.
        float x = frac - (float)PADI;
        float a_signed = asp;                 // (-1)^j * asp, j starting even
        for (int j = 0; j < FLEN - 1; ++j) {
            float hc   = s_cj[j] * ch - s_sj[j] * sh;   // cos(pi*x/40)
            float hann = 0.5f + 0.5f * hc;
            float val  = a_signed * __builtin_amdgcn_rcpf(x) * hann;
            int idx = base + j;
            if (idx >= 0 && idx < RIRLEN) atomicAdd(&s_rir[idx], val);
            x += 1.0f;
            a_signed = -a_signed;
        }
    }

    __syncthreads();

    // coalesced float4 write-out of this batch's RIR
    float4* o4 = (float4*)(out + (size_t)b * RIRLEN);
    const float4* s4 = (const float4*)s_rir;
    for (int i = tid; i < RIRLEN / 4; i += NTHREADS) o4[i] = s4[i];

    // time-of-arrival for this batch
    if (tid == 0) {
        float dx = mx - sx, dy = my - sy, dz = mz - sz;
        float d  = sqrtf(dx * dx + dy * dy + dz * dz);
        out[(size_t)NB * RIRLEN + b] = 40.0f + d * FS / C;
    }
}

extern "C" void kernel_launch(void* const* d_in, const int* in_sizes, int n_in,
                              void* d_out, int out_size, void* d_ws, size_t ws_size,
                              hipStream_t stream) {
    const float* in = (const float*)d_in[0];
    float* out = (float*)d_out;
    rir_kernel<<<dim3(NB), dim3(NTHREADS), 0, stream>>>(in, out);
}

// Round 2
// 107.035 us; speedup vs baseline: 2.0381x; 2.0381x over previous
//
#include <hip/hip_runtime.h>
#include <math.h>

#define NB 256
#define NIMG 1561
#define RIRLEN 8000
#define FLEN 81
#define PADI 40
#define NTHREADS 1024
#define NSEG 125      // 8000 / 64
#define NBUCKET 126   // bucket = (base+64)>>6, base in [-40, 7999] -> 0..125

// ---------------------------------------------------------------------------
// Compile-time image-lattice table: all g in [-10,10]^3 with |g|_1 <= 10,
// meshgrid(ij) lexicographic order. Packed:
//   bits 0-4: x+10, 5-9: y+10, 10-14: z+10, 15-19: |g|_1
// ---------------------------------------------------------------------------
struct ImgTab { unsigned int v[NIMG]; };

constexpr ImgTab build_tab() {
    ImgTab t{};
    int n = 0;
    for (int x = -10; x <= 10; ++x)
        for (int y = -10; y <= 10; ++y)
            for (int z = -10; z <= 10; ++z) {
                int ax = x < 0 ? -x : x;
                int ay = y < 0 ? -y : y;
                int az = z < 0 ? -z : z;
                int l1 = ax + ay + az;
                if (l1 <= 10) {
                    t.v[n++] = (unsigned)(x + 10) | ((unsigned)(y + 10) << 5) |
                               ((unsigned)(z + 10) << 10) | ((unsigned)l1 << 15);
                }
            }
    return t;
}

constexpr int tab_count() {
    int n = 0;
    for (int x = -10; x <= 10; ++x)
        for (int y = -10; y <= 10; ++y)
            for (int z = -10; z <= 10; ++z) {
                int ax = x < 0 ? -x : x;
                int ay = y < 0 ? -y : y;
                int az = z < 0 ? -z : z;
                if (ax + ay + az <= 10) ++n;
            }
    return n;
}
static_assert(tab_count() == NIMG, "image count mismatch");

__constant__ ImgTab c_tab = build_tab();

__global__ __launch_bounds__(NTHREADS) void
rir_kernel(const float* __restrict__ in, float* __restrict__ out) {
    // sorted image records: (asp, ch, sh, frac) + base index
    __shared__ float4 s_rec[NIMG];
    __shared__ int    s_base[NIMG];
    __shared__ float2 s_cs[FLEN];        // (cos, sin)(pi*(j-40)/40)
    __shared__ float  s_trpow[11];       // tr^k
    __shared__ int    s_hist[NBUCKET];
    __shared__ int    s_start[NBUCKET + 1];
    __shared__ int    s_cursor[NBUCKET];
    __shared__ int    s_scan[128];

    const int b   = blockIdx.x;
    const int tid = threadIdx.x;
    const float* p = in + b * 10;

    if (tid < FLEN) {
        float a = (float)(tid - PADI) * (1.0f / 40.0f);
        s_cs[tid] = make_float2(cospif(a), sinpif(a));
    }
    if (tid < NBUCKET) s_hist[tid] = 0;
    if (tid == 0) {
        float tr = sqrtf(1.0f - p[9]);
        float pw = 1.0f;
        for (int k = 0; k <= 10; ++k) { s_trpow[k] = pw; pw *= tr; }
    }
    __syncthreads();

    const float rx = p[0], ry = p[1], rz = p[2];
    const float mx = p[3] * rx, my = p[4] * ry, mz = p[5] * rz;
    const float sx = p[6] * rx, sy = p[7] * ry, sz = p[8] * rz;
    const float K = 16000.0f / 343.0f;
    const float INV_PI = 0.31830988618379067154f;

    // ---- phase 1: per-image parameters + bucket histogram ----
    float4 rec[2] = {make_float4(0,0,0,0), make_float4(0,0,0,0)};
    int ibase[2] = {0, 0};
    int ibkt[2]  = {0, 0};
    bool ivalid[2] = {false, false};

    for (int u = 0; u < 2; ++u) {
        int i = tid + u * NTHREADS;
        if (i < NIMG) {
            unsigned v = c_tab.v[i];
            int gx = (int)(v & 31u) - 10;
            int gy = (int)((v >> 5) & 31u) - 10;
            int gz = (int)((v >> 10) & 31u) - 10;
            int l1 = (int)(v >> 15);

            float ix = (gx & 1) ? rx * (float)(gx + 1) - sx : rx * (float)gx + sx;
            float iy = (gy & 1) ? ry * (float)(gy + 1) - sy : ry * (float)gy + sy;
            float iz = (gz & 1) ? rz * (float)(gz + 1) - sz : rz * (float)gz + sz;

            float dx = ix - mx, dy = iy - my, dz = iz - mz;
            float dist = sqrtf(dx * dx + dy * dy + dz * dz);

            float amp   = s_trpow[l1] / dist;
            float delay = dist * K;
            float dlc   = ceilf(delay);
            float frac  = dlc - delay;            // exact (Sterbenz)
            int   base  = (int)dlc - PADI;

            if (base < RIRLEN) {
                // frac==0 -> exact-integer delay; substitute 2^-20 so the
                // center tap reproduces amp to 1 ulp (rcp(2^-20) exact) and
                // side taps pick up only ~1e-6*amp.
                float fr = fmaxf(frac, 9.5367431640625e-7f);
                // sin(pi*f)/pi, linearized below 1e-3 (better accuracy, and
                // makes the frac==0 spike exact)
                float spf = (fr < 1.0e-3f) ? fr : (sinpif(fr) * INV_PI);
                rec[u] = make_float4(amp * spf,
                                     cospif(fr * 0.025f),
                                     sinpif(fr * 0.025f),
                                     fr);
                ibase[u]  = base;
                ibkt[u]   = (base + 64) >> 6;
                ivalid[u] = true;
                atomicAdd(&s_hist[ibkt[u]], 1);
            }
        }
    }
    __syncthreads();

    // ---- exclusive scan of histogram -> s_start (Hillis-Steele, 128 wide) ----
    if (tid < 128) s_scan[tid] = (tid < NBUCKET) ? s_hist[tid] : 0;
    __syncthreads();
    for (int d = 1; d < 128; d <<= 1) {
        int y = 0;
        if (tid < 128 && tid >= d) y = s_scan[tid - d];
        __syncthreads();
        if (tid < 128) s_scan[tid] += y;
        __syncthreads();
    }
    if (tid < NBUCKET) {
        s_start[tid + 1] = s_scan[tid];               // inclusive -> start[t+1]
        s_cursor[tid]    = (tid == 0) ? 0 : s_scan[tid - 1];
        if (tid == 0) s_start[0] = 0;
    }
    __syncthreads();

    // ---- scatter records into bucket-sorted order ----
    for (int u = 0; u < 2; ++u) {
        if (ivalid[u]) {
            int pos = atomicAdd(&s_cursor[ibkt[u]], 1);
            s_rec[pos]  = rec[u];
            s_base[pos] = ibase[u];
        }
    }
    __syncthreads();

    // ---- phase 2: gather. each wave owns 64-sample output segments ----
    const int wave = tid >> 6;
    const int lane = tid & 63;
    for (int s = wave; s < NSEG; s += NTHREADS / 64) {
        const int n_i = (s << 6) + lane;
        float acc = 0.0f;
        int b0 = (s > 0) ? (s - 1) : 0;
        int b1 = (s + 1 < NBUCKET) ? (s + 1) : (NBUCKET - 1);
        int lo = s_start[b0], hi = s_start[b1 + 1];
        for (int k = lo; k < hi; ++k) {
            float4 r  = s_rec[k];     // broadcast (all lanes same addr)
            int  base = s_base[k];
            int  j    = n_i - base;   // tap index for this lane
            if ((unsigned)j < 80u) {  // j==80 tap: hann==0, dropped
                float2 cs = s_cs[j];
                float hc   = fmaf(cs.x, r.y, -(cs.y * r.z));  // cos(pi*x/40)
                float hann = fmaf(0.5f, hc, 0.5f);
                float x    = (float)(j - PADI) + r.w;
                float v    = r.x * __builtin_amdgcn_rcpf(x) * hann;
                acc += (j & 1) ? -v : v;
            }
        }
        out[(size_t)b * RIRLEN + n_i] = acc;
    }

    // time-of-arrival
    if (tid == 0) {
        float dx = mx - sx, dy = my - sy, dz = mz - sz;
        out[(size_t)NB * RIRLEN + b] = 40.0f + sqrtf(dx * dx + dy * dy + dz * dz) * K;
    }
}

extern "C" void kernel_launch(void* const* d_in, const int* in_sizes, int n_in,
                              void* d_out, int out_size, void* d_ws, size_t ws_size,
                              hipStream_t stream) {
    const float* in = (const float*)d_in[0];
    float* out = (float*)d_out;
    rir_kernel<<<dim3(NB), dim3(NTHREADS), 0, stream>>>(in, out);
}

// Round 3
// 86.225 us; speedup vs baseline: 2.5300x; 1.2413x over previous
//
#include <hip/hip_runtime.h>
#include <math.h>

#define NB 256
#define NIMG 1561
#define RIRLEN 8000
#define FLEN 81
#define PADI 40
#define NTHREADS 1024
#define NSEG 125      // 8000 / 64
#define NBUCKET 126   // bucket = (base+64)>>6, base in [-40, 7999] -> 0..125

// ---------------------------------------------------------------------------
// Compile-time image-lattice table: all g in [-10,10]^3 with |g|_1 <= 10,
// meshgrid(ij) lexicographic order. Packed:
//   bits 0-4: x+10, 5-9: y+10, 10-14: z+10, 15-19: |g|_1
// ---------------------------------------------------------------------------
struct ImgTab { unsigned int v[NIMG]; };

constexpr ImgTab build_tab() {
    ImgTab t{};
    int n = 0;
    for (int x = -10; x <= 10; ++x)
        for (int y = -10; y <= 10; ++y)
            for (int z = -10; z <= 10; ++z) {
                int ax = x < 0 ? -x : x;
                int ay = y < 0 ? -y : y;
                int az = z < 0 ? -z : z;
                int l1 = ax + ay + az;
                if (l1 <= 10) {
                    t.v[n++] = (unsigned)(x + 10) | ((unsigned)(y + 10) << 5) |
                               ((unsigned)(z + 10) << 10) | ((unsigned)l1 << 15);
                }
            }
    return t;
}

constexpr int tab_count() {
    int n = 0;
    for (int x = -10; x <= 10; ++x)
        for (int y = -10; y <= 10; ++y)
            for (int z = -10; z <= 10; ++z) {
                int ax = x < 0 ? -x : x;
                int ay = y < 0 ? -y : y;
                int az = z < 0 ? -z : z;
                if (ax + ay + az <= 10) ++n;
            }
    return n;
}
static_assert(tab_count() == NIMG, "image count mismatch");

__constant__ ImgTab c_tab = build_tab();

// Record per image (bucket-sorted): (S, cd, sd, d)
//   S  = (-1)^dlc * amp * sin(pi*frac)/pi        (frac bumped to >=2^-20)
//   cd = cos(pi*d/40), sd = sin(pi*d/40)
//   d  = exact float delay (dlc - frac)
// Tap value for output sample n:  (-1)^n * S * hann(x) / x,  x = n - d.
__global__ __launch_bounds__(NTHREADS) void
rir_kernel(const float* __restrict__ in, float* __restrict__ out) {
    __shared__ float4 s_rec[NIMG];
    __shared__ float  s_trpow[11];       // tr^k
    __shared__ int    s_hist[NBUCKET];
    __shared__ int    s_start[NBUCKET + 1];
    __shared__ int    s_cursor[NBUCKET];
    __shared__ int    s_scan[128];

    const int b   = blockIdx.x;
    const int tid = threadIdx.x;
    const float* p = in + b * 10;

    if (tid < NBUCKET) s_hist[tid] = 0;
    if (tid == 0) {
        float tr = sqrtf(1.0f - p[9]);
        float pw = 1.0f;
        for (int k = 0; k <= 10; ++k) { s_trpow[k] = pw; pw *= tr; }
    }
    __syncthreads();

    const float rx = p[0], ry = p[1], rz = p[2];
    const float mx = p[3] * rx, my = p[4] * ry, mz = p[5] * rz;
    const float sx = p[6] * rx, sy = p[7] * ry, sz = p[8] * rz;
    const float K = 16000.0f / 343.0f;
    const float INV_PI = 0.31830988618379067154f;

    // ---- phase 1: per-image parameters + bucket histogram ----
    float4 rec[2];
    int ibase[2] = {0, 0};
    int ibkt[2]  = {0, 0};
    bool ivalid[2] = {false, false};

    for (int u = 0; u < 2; ++u) {
        int i = tid + u * NTHREADS;
        if (i < NIMG) {
            unsigned v = c_tab.v[i];
            int gx = (int)(v & 31u) - 10;
            int gy = (int)((v >> 5) & 31u) - 10;
            int gz = (int)((v >> 10) & 31u) - 10;
            int l1 = (int)(v >> 15);

            float ix = (gx & 1) ? rx * (float)(gx + 1) - sx : rx * (float)gx + sx;
            float iy = (gy & 1) ? ry * (float)(gy + 1) - sy : ry * (float)gy + sy;
            float iz = (gz & 1) ? rz * (float)(gz + 1) - sz : rz * (float)gz + sz;

            float dx = ix - mx, dy = iy - my, dz = iz - mz;
            float dist = sqrtf(dx * dx + dy * dy + dz * dz);

            float amp  = s_trpow[l1] / dist;
            float d    = dist * K;
            float dlc  = ceilf(d);
            float frac = dlc - d;                 // exact (Sterbenz)
            int   idlc = (int)dlc;
            int   base = idlc - PADI;

            if (base < RIRLEN) {
                // frac==0 bump: center tap becomes S*rcp(2^-20) == amp to 1 ulp
                float frb = fmaxf(frac, 9.5367431640625e-7f);
                float spf = (frb < 1.0e-3f) ? frb : (sinpif(frb) * INV_PI);
                float S   = amp * spf;
                if (idlc & 1) S = -S;             // (-1)^dlc
                float db  = dlc - frb;            // == d (exact) except bump case
                rec[u] = make_float4(S,
                                     cospif(db * 0.025f),
                                     sinpif(db * 0.025f),
                                     db);
                ibase[u]  = base;
                ibkt[u]   = (base + 64) >> 6;
                ivalid[u] = true;
                atomicAdd(&s_hist[ibkt[u]], 1);
            }
        }
    }
    __syncthreads();

    // ---- exclusive scan of histogram -> s_start (Hillis-Steele, 128 wide) ----
    if (tid < 128) s_scan[tid] = (tid < NBUCKET) ? s_hist[tid] : 0;
    __syncthreads();
    for (int d = 1; d < 128; d <<= 1) {
        int y = 0;
        if (tid < 128 && tid >= d) y = s_scan[tid - d];
        __syncthreads();
        if (tid < 128) s_scan[tid] += y;
        __syncthreads();
    }
    if (tid < NBUCKET) {
        s_start[tid + 1] = s_scan[tid];               // inclusive -> start[t+1]
        s_cursor[tid]    = (tid == 0) ? 0 : s_scan[tid - 1];
        if (tid == 0) s_start[0] = 0;
    }
    __syncthreads();

    // ---- scatter records into bucket-sorted order ----
    for (int u = 0; u < 2; ++u) {
        if (ivalid[u]) {
            int pos = atomicAdd(&s_cursor[ibkt[u]], 1);
            s_rec[pos] = rec[u];
        }
    }
    __syncthreads();

    // ---- phase 2: gather. each wave owns 64-sample output segments ----
    const int wave = tid >> 6;
    const int lane = tid & 63;
    for (int s = wave; s < NSEG; s += NTHREADS / 64) {
        const int   n_i = (s << 6) + lane;
        const float fn  = (float)n_i;
        // per-lane constants for this segment
        const float cn = cospif(fn * 0.025f);     // cos(pi*n/40)
        const float sn = sinpif(fn * 0.025f);     // sin(pi*n/40)
        float acc = 0.0f;

        int b0 = (s > 0) ? (s - 1) : 0;
        int b1 = (s + 1 < NBUCKET) ? (s + 1) : (NBUCKET - 1);
        int lo = s_start[b0], hi = s_start[b1 + 1];
#pragma clang loop unroll_count(4)
        for (int k = lo; k < hi; ++k) {
            float4 r = s_rec[k];                  // broadcast, conflict-free
            float x  = fn - r.w;                  // exact (Sterbenz)
            float ax = fabsf(x);
            float xb = (x == 0.0f) ? 9.5367431640625e-7f : x;
            float hc = fmaf(cn, r.y, sn * r.z);   // cos(pi*x/40)
            float hann = fmaf(0.5f, hc, 0.5f);
            hann = (ax < 40.0f) ? hann : 0.0f;    // window + segment-miss mask
            acc  = fmaf(r.x * __builtin_amdgcn_rcpf(xb), hann, acc);
        }
        float sgn = (n_i & 1) ? -1.0f : 1.0f;     // (-1)^n
        out[(size_t)b * RIRLEN + n_i] = acc * sgn;
    }

    // time-of-arrival
    if (tid == 0) {
        float dx = mx - sx, dy = my - sy, dz = mz - sz;
        out[(size_t)NB * RIRLEN + b] = 40.0f + sqrtf(dx * dx + dy * dy + dz * dz) * K;
    }
}

extern "C" void kernel_launch(void* const* d_in, const int* in_sizes, int n_in,
                              void* d_out, int out_size, void* d_ws, size_t ws_size,
                              hipStream_t stream) {
    const float* in = (const float*)d_in[0];
    float* out = (float*)d_out;
    rir_kernel<<<dim3(NB), dim3(NTHREADS), 0, stream>>>(in, out);
}